// Round 1
// baseline (5053.181 us; speedup 1.0000x reference)
//
#include <hip/hip_runtime.h>
#include <cstdint>
#include <cstddef>

// ---------------------------------------------------------------------------
// GCN regression model, fp32 end-to-end.
//   deg/dinv once; per layer: GEMM (W in LDS) + scatter-add over edges.
//   Algebra: A(XW) == (AX)W  -> aggregate on the cheaper dim per layer.
//            hs = h*dinv; agg[d] = dinv[d]*(sum_{src->d} hs[src] + hs[d])
//            -> scatter is a pure add, no per-edge norm multiply.
//   Pool: (mean_g h4) @ Wfc == mean_g (h4 @ Wfc) -> per-node scalar dot first.
// ---------------------------------------------------------------------------

static __global__ void deg_kernel(const int* __restrict__ dst, int* __restrict__ deg, int E) {
    int t = blockIdx.x * 256 + threadIdx.x;
    if (t < E) atomicAdd(&deg[dst[t]], 1);
}

static __global__ void dinv_kernel(const int* __restrict__ deg, float* __restrict__ dinv, int N) {
    int t = blockIdx.x * 256 + threadIdx.x;
    if (t < N) dinv[t] = rsqrtf((float)deg[t] + 1.0f);
}

// o[row] = x[row] * dinv[row], dim 64, float4 per thread
static __global__ void scale_kernel(const float* __restrict__ x, const float* __restrict__ dinv,
                                    float* __restrict__ o, int N) {
    int t = blockIdx.x * 256 + threadIdx.x;
    if (t >= N * 16) return;
    int row = t >> 4;
    int c = (t & 15) * 4;
    float d = dinv[row];
    float4 v = *(const float4*)&x[(size_t)row * 64 + c];
    v.x *= d; v.y *= d; v.z *= d; v.w *= d;
    *(float4*)&o[(size_t)row * 64 + c] = v;
}

// S[dst] += in[src]  (dim = 4*D4), one thread per (edge, 4 dims)
template <int D4>
static __global__ void scatter_kernel(const float* __restrict__ in, float* __restrict__ S,
                                      const int* __restrict__ src, const int* __restrict__ dst, int E) {
    constexpr int LG = (D4 == 16) ? 4 : 3;
    constexpr int D = D4 * 4;
    int t = blockIdx.x * 256 + threadIdx.x;
    if (t >= E * D4) return;
    int e = t >> LG;
    int c = (t & (D4 - 1)) * 4;
    int s = src[e], d = dst[e];
    float4 v = *(const float4*)&in[(size_t)s * D + c];
    float* p = &S[(size_t)d * D + c];
    unsafeAtomicAdd(p + 0, v.x);
    unsafeAtomicAdd(p + 1, v.y);
    unsafeAtomicAdd(p + 2, v.z);
    unsafeAtomicAdd(p + 3, v.w);
}

// o = dinv*(S+M)           (BR=false: layer-1 pre-aggregation of X)
// o = relu(dinv*(S+M)+b)   (BR=true : layers 2..4 epilogue)
template <int D4, bool BR>
static __global__ void finalize_kernel(const float* __restrict__ M, const float* __restrict__ S,
                                       const float* __restrict__ dinv, const float* __restrict__ b,
                                       float* __restrict__ o, int N) {
    constexpr int D = D4 * 4;
    int t = blockIdx.x * 256 + threadIdx.x;
    if (t >= N * D4) return;
    int row = t / D4;
    int c = (t & (D4 - 1)) * 4;
    float4 s = *(const float4*)&S[(size_t)row * D + c];
    float4 m = *(const float4*)&M[(size_t)row * D + c];
    float dv = dinv[row];
    float4 r;
    r.x = (s.x + m.x) * dv;
    r.y = (s.y + m.y) * dv;
    r.z = (s.z + m.z) * dv;
    r.w = (s.w + m.w) * dv;
    if (BR) {
        float4 bv = *(const float4*)&b[c];
        r.x = fmaxf(r.x + bv.x, 0.f);
        r.y = fmaxf(r.y + bv.y, 0.f);
        r.z = fmaxf(r.z + bv.z, 0.f);
        r.w = fmaxf(r.w + bv.w, 0.f);
    }
    *(float4*)&o[(size_t)row * D + c] = r;
}

// out = Xin @ W (+epilogue). W fully resident in LDS. 256 threads, RTx4 tile/thread.
// MODE 0: out = relu(acc + bias[col])      (layer 1)
// MODE 1: out = acc * dinv[row]            (layers 2..4: pre-scatter scale)
template <int K, int OUT, int RT, int MODE>
__launch_bounds__(256)
static __global__ void gemm_kernel(const float* __restrict__ Xin, const float* __restrict__ W,
                                   const float* __restrict__ bias, const float* __restrict__ dinv,
                                   float* __restrict__ out, int N) {
    constexpr int CT = OUT / 4;        // threads along columns
    constexpr int RTH = 256 / CT;      // threads along rows
    constexpr int RB = RTH * RT;       // rows per block
    constexpr int KP = K + 4;          // padded X stride (kills k-stride bank conflicts)
    __shared__ float Wl[K * OUT];
    __shared__ float Xl[RB * KP];

    const int tid = threadIdx.x;
    const int row0 = blockIdx.x * RB;

    for (int idx = tid; idx < K * OUT / 4; idx += 256)
        ((float4*)Wl)[idx] = ((const float4*)W)[idx];

    constexpr int KC = K / 4;
    for (int idx = tid; idx < RB * KC; idx += 256) {
        int r = idx / KC;
        int kc = idx - r * KC;
        int g = row0 + r;
        float4 v = (g < N) ? ((const float4*)(Xin + (size_t)g * K))[kc]
                           : make_float4(0.f, 0.f, 0.f, 0.f);
        *(float4*)&Xl[r * KP + kc * 4] = v;
    }
    __syncthreads();

    const int tx = tid % CT, ty = tid / CT;
    const int col0 = tx * 4;
    float4 acc[RT];
#pragma unroll
    for (int i = 0; i < RT; i++) acc[i] = make_float4(0.f, 0.f, 0.f, 0.f);

#pragma unroll 4
    for (int k = 0; k < K; k += 4) {
        float4 w0 = *(float4*)&Wl[(k + 0) * OUT + col0];
        float4 w1 = *(float4*)&Wl[(k + 1) * OUT + col0];
        float4 w2 = *(float4*)&Wl[(k + 2) * OUT + col0];
        float4 w3 = *(float4*)&Wl[(k + 3) * OUT + col0];
#pragma unroll
        for (int i = 0; i < RT; i++) {
            float4 xv = *(float4*)&Xl[(ty * RT + i) * KP + k];
            acc[i].x += xv.x * w0.x + xv.y * w1.x + xv.z * w2.x + xv.w * w3.x;
            acc[i].y += xv.x * w0.y + xv.y * w1.y + xv.z * w2.y + xv.w * w3.y;
            acc[i].z += xv.x * w0.z + xv.y * w1.z + xv.z * w2.z + xv.w * w3.z;
            acc[i].w += xv.x * w0.w + xv.y * w1.w + xv.z * w2.w + xv.w * w3.w;
        }
    }

    if (MODE == 0) {
        float4 bv = *(const float4*)&bias[col0];
#pragma unroll
        for (int i = 0; i < RT; i++) {
            int g = row0 + ty * RT + i;
            if (g < N) {
                float4 r;
                r.x = fmaxf(acc[i].x + bv.x, 0.f);
                r.y = fmaxf(acc[i].y + bv.y, 0.f);
                r.z = fmaxf(acc[i].z + bv.z, 0.f);
                r.w = fmaxf(acc[i].w + bv.w, 0.f);
                *(float4*)&out[(size_t)g * OUT + col0] = r;
            }
        }
    } else {
#pragma unroll
        for (int i = 0; i < RT; i++) {
            int g = row0 + ty * RT + i;
            if (g < N) {
                float d = dinv[g];
                float4 r;
                r.x = acc[i].x * d; r.y = acc[i].y * d;
                r.z = acc[i].z * d; r.w = acc[i].w * d;
                *(float4*)&out[(size_t)g * OUT + col0] = r;
            }
        }
    }
}

// per-node scalar dot with Wfc, then segment-sum into psum/pcnt (batch is sorted
// -> LDS pre-reduction, few global atomics per block)
static __global__ void pool_kernel(const float* __restrict__ h, const float* __restrict__ Wfc,
                                   const int* __restrict__ batch, float* __restrict__ psum,
                                   int* __restrict__ pcnt, int N) {
    __shared__ float wl[32];
    __shared__ float gsum[64];
    __shared__ int gcnt[64];
    __shared__ int sbase;
    int tid = threadIdx.x;
    if (tid < 32) wl[tid] = Wfc[tid];
    if (tid < 64) { gsum[tid] = 0.f; gcnt[tid] = 0; }
    if (tid == 0) sbase = batch[blockIdx.x * 256];
    __syncthreads();

    int n = blockIdx.x * 256 + tid;
    if (n < N) {
        const float4* hp = (const float4*)(h + (size_t)n * 32);
        float val = 0.f;
#pragma unroll
        for (int j = 0; j < 8; j++) {
            float4 hv = hp[j];
            val += hv.x * wl[j * 4 + 0] + hv.y * wl[j * 4 + 1] +
                   hv.z * wl[j * 4 + 2] + hv.w * wl[j * 4 + 3];
        }
        int g = batch[n];
        int rel = g - sbase;
        if ((unsigned)rel < 64u) {
            atomicAdd(&gsum[rel], val);
            atomicAdd(&gcnt[rel], 1);
        } else {
            unsafeAtomicAdd(&psum[g], val);
            atomicAdd(&pcnt[g], 1);
        }
    }
    __syncthreads();
    if (tid < 64 && gcnt[tid] > 0) {
        unsafeAtomicAdd(&psum[sbase + tid], gsum[tid]);
        atomicAdd(&pcnt[sbase + tid], gcnt[tid]);
    }
}

static __global__ void final_kernel(const float* __restrict__ psum, const int* __restrict__ pcnt,
                                    const float* __restrict__ bfc, float* __restrict__ out, int G) {
    int t = threadIdx.x;
    if (t < G) {
        float c = (float)pcnt[t];
        out[t] = psum[t] / fmaxf(c, 1.f) + bfc[0];
    }
}

extern "C" void kernel_launch(void* const* d_in, const int* in_sizes, int n_in,
                              void* d_out, int out_size, void* d_ws, size_t ws_size,
                              hipStream_t stream) {
    const float* x    = (const float*)d_in[0];
    const int*   ei   = (const int*)d_in[1];
    const int*   batch= (const int*)d_in[2];
    const float* W1   = (const float*)d_in[4];
    const float* b1   = (const float*)d_in[5];
    const float* W2   = (const float*)d_in[6];
    const float* b2   = (const float*)d_in[7];
    const float* W3   = (const float*)d_in[8];
    const float* b3   = (const float*)d_in[9];
    const float* W4   = (const float*)d_in[10];
    const float* b4   = (const float*)d_in[11];
    const float* Wfc  = (const float*)d_in[12];
    const float* bfc  = (const float*)d_in[13];
    float* out = (float*)d_out;

    const int N = in_sizes[0] / 64;
    const int E = in_sizes[1] / 2;
    const int G = out_size;
    const int* srcp = ei;
    const int* dstp = ei + E;

    // workspace layout (floats)
    float* wsf = (float*)d_ws;
    const size_t Npad = ((size_t)N + 1023) / 1024 * 1024;
    float* dinv = wsf;
    int*   deg  = (int*)(wsf + Npad);
    float* psum = wsf + 2 * Npad;
    int*   pcnt = (int*)(wsf + 2 * Npad + 256);
    float* S    = wsf + 2 * Npad + 1024;
    const size_t SSZ = Npad * 64;
    float* T1 = S + SSZ;
    float* T2 = T1 + SSZ;
    float* H1 = T2 + SSZ;   // Npad*128

    const int gE   = (E + 255) / 256;
    const int gN   = (N + 255) / 256;
    const int gN16 = (N * 16 + 255) / 256;
    const int gN8  = (N * 8 + 255) / 256;
    const int gE16 = (int)(((long long)E * 16 + 255) / 256);
    const int gE8  = (int)(((long long)E * 8 + 255) / 256);

    hipMemsetAsync(deg, 0, sizeof(int) * N, stream);
    hipMemsetAsync(psum, 0, 512 * sizeof(float), stream);
    deg_kernel<<<gE, 256, 0, stream>>>(dstp, deg, E);
    dinv_kernel<<<gN, 256, 0, stream>>>(deg, dinv, N);

    // ---- layer 1: aggregate X (dim 64) first, then GEMM 64->128 + bias + relu
    scale_kernel<<<gN16, 256, 0, stream>>>(x, dinv, T1, N);
    hipMemsetAsync(S, 0, (size_t)N * 64 * sizeof(float), stream);
    scatter_kernel<16><<<gE16, 256, 0, stream>>>(T1, S, srcp, dstp, E);
    finalize_kernel<16, false><<<gN16, 256, 0, stream>>>(T1, S, dinv, nullptr, T2, N);
    gemm_kernel<64, 128, 4, 0><<<(N + 31) / 32, 256, 0, stream>>>(T2, W1, b1, nullptr, H1, N);

    // ---- layer 2: GEMM 128->64 (scale by dinv), scatter, finalize(bias+relu)
    gemm_kernel<128, 64, 2, 1><<<(N + 31) / 32, 256, 0, stream>>>(H1, W2, nullptr, dinv, T1, N);
    hipMemsetAsync(S, 0, (size_t)N * 64 * sizeof(float), stream);
    scatter_kernel<16><<<gE16, 256, 0, stream>>>(T1, S, srcp, dstp, E);
    finalize_kernel<16, true><<<gN16, 256, 0, stream>>>(T1, S, dinv, b2, T2, N);

    // ---- layer 3: GEMM 64->64
    gemm_kernel<64, 64, 4, 1><<<(N + 63) / 64, 256, 0, stream>>>(T2, W3, nullptr, dinv, T1, N);
    hipMemsetAsync(S, 0, (size_t)N * 64 * sizeof(float), stream);
    scatter_kernel<16><<<gE16, 256, 0, stream>>>(T1, S, srcp, dstp, E);
    finalize_kernel<16, true><<<gN16, 256, 0, stream>>>(T1, S, dinv, b3, T2, N);

    // ---- layer 4: GEMM 64->32
    gemm_kernel<64, 32, 4, 1><<<(N + 127) / 128, 256, 0, stream>>>(T2, W4, nullptr, dinv, T1, N);
    hipMemsetAsync(S, 0, (size_t)N * 32 * sizeof(float), stream);
    scatter_kernel<8><<<gE8, 256, 0, stream>>>(T1, S, srcp, dstp, E);
    finalize_kernel<8, true><<<gN8, 256, 0, stream>>>(T1, S, dinv, b4, T2, N);

    // ---- pool + fc
    pool_kernel<<<gN, 256, 0, stream>>>(T2, Wfc, batch, psum, pcnt, N);
    final_kernel<<<1, 256, 0, stream>>>(psum, pcnt, bfc, out, G);
}

// Round 2
// 637.645 us; speedup vs baseline: 7.9248x; 7.9248x over previous
//
#include <hip/hip_runtime.h>
#include <cstdint>
#include <cstddef>

// ---------------------------------------------------------------------------
// GCN regression model, fp32. Round 2: scatter-atomics -> CSR + register gather.
//   CSR (grouped by dst, col=src) built per call: deg -> 3-kernel scan -> fill.
//   Per layer: GEMM (W in LDS, epilogue fused) then gather_kernel:
//     out[d] = act( dinv[d]*(sum_{s->d} hs[s] + hs[d]) + b )
//   16 threads/node (dim64) walk the edge list with __shfl-broadcast indices.
//   Pool: (mean_g h4)@Wfc == mean_g(h4@Wfc) -> per-node scalar dot, segment mean.
// ---------------------------------------------------------------------------

static __global__ void deg_kernel(const int* __restrict__ dst, int* __restrict__ deg, int E) {
    int t = blockIdx.x * 256 + threadIdx.x;
    if (t < E) atomicAdd(&deg[dst[t]], 1);
}

static __global__ void dinv_kernel(const int* __restrict__ deg, float* __restrict__ dinv, int N) {
    int t = blockIdx.x * 256 + threadIdx.x;
    if (t < N) dinv[t] = rsqrtf((float)deg[t] + 1.0f);
}

// ---- exclusive scan of deg -> rowptr (N=100k: 391 block sums, single-block pass)
static __global__ void blocksum_kernel(const int* __restrict__ deg, int* __restrict__ bsum, int N) {
    __shared__ int s[256];
    int t = blockIdx.x * 256 + threadIdx.x;
    s[threadIdx.x] = (t < N) ? deg[t] : 0;
    __syncthreads();
    for (int off = 128; off > 0; off >>= 1) {
        if (threadIdx.x < off) s[threadIdx.x] += s[threadIdx.x + off];
        __syncthreads();
    }
    if (threadIdx.x == 0) bsum[blockIdx.x] = s[0];
}

// single block, nb <= 512
static __global__ void scanb_kernel(int* __restrict__ bsum, int nb) {
    __shared__ int s[512];
    int t = threadIdx.x;
    int v = (t < nb) ? bsum[t] : 0;
    s[t] = v;
    __syncthreads();
    for (int off = 1; off < 512; off <<= 1) {
        int u = (t >= off) ? s[t - off] : 0;
        __syncthreads();
        s[t] += u;
        __syncthreads();
    }
    if (t < nb) bsum[t] = s[t] - v;  // exclusive
}

static __global__ void scanc_kernel(const int* __restrict__ deg, const int* __restrict__ boff,
                                    int* __restrict__ rowptr, int* __restrict__ fill, int N, int E) {
    __shared__ int s[256];
    int t = blockIdx.x * 256 + threadIdx.x;
    int v = (t < N) ? deg[t] : 0;
    s[threadIdx.x] = v;
    __syncthreads();
    for (int off = 1; off < 256; off <<= 1) {
        int u = (threadIdx.x >= off) ? s[threadIdx.x - off] : 0;
        __syncthreads();
        s[threadIdx.x] += u;
        __syncthreads();
    }
    if (t < N) {
        int excl = s[threadIdx.x] - v + boff[blockIdx.x];
        rowptr[t] = excl;
        fill[t] = excl;
    }
    if (t == 0) rowptr[N] = E;
}

static __global__ void fill_kernel(const int* __restrict__ src, const int* __restrict__ dst,
                                   int* __restrict__ fill, int* __restrict__ col, int E) {
    int t = blockIdx.x * 256 + threadIdx.x;
    if (t < E) {
        int d = dst[t];
        int p = atomicAdd(&fill[d], 1);
        col[p] = src[t];
    }
}

// o[row] = x[row] * dinv[row], dim 64
static __global__ void scale_kernel(const float* __restrict__ x, const float* __restrict__ dinv,
                                    float* __restrict__ o, int N) {
    int t = blockIdx.x * 256 + threadIdx.x;
    if (t >= N * 16) return;
    int row = t >> 4;
    int c = (t & 15) * 4;
    float d = dinv[row];
    float4 v = *(const float4*)&x[(size_t)row * 64 + c];
    v.x *= d; v.y *= d; v.z *= d; v.w *= d;
    *(float4*)&o[(size_t)row * 64 + c] = v;
}

// out[d] = dinv[d]*(sum_{s in row d} hs[s] + hs[d])  [+bias, relu if BR]
// D4 float4s per row; D4 threads per node; col[] broadcast via __shfl width=D4.
template <int D4, bool BR>
__launch_bounds__(256)
static __global__ void gather_kernel(const float* __restrict__ hs, const int* __restrict__ rowptr,
                                     const int* __restrict__ col, const float* __restrict__ dinv,
                                     const float* __restrict__ b, float* __restrict__ out, int N) {
    constexpr int D = D4 * 4;
    constexpr int NPB = 256 / D4;
    constexpr int LG = (D4 == 16) ? 4 : 3;
    const int lane = threadIdx.x & (D4 - 1);
    const int node = blockIdx.x * NPB + (threadIdx.x >> LG);
    if (node >= N) return;
    const int beg = rowptr[node];
    const int end = rowptr[node + 1];
    float4 acc = *(const float4*)&hs[(size_t)node * D + lane * 4];  // self loop
    for (int e = beg; e < end; e += D4) {
        int myc = (e + lane < end) ? col[e + lane] : 0;
        int m = min(D4, end - e);
        for (int j = 0; j < m; ++j) {
            int s = __shfl(myc, j, D4);
            float4 v = *(const float4*)&hs[(size_t)s * D + lane * 4];
            acc.x += v.x; acc.y += v.y; acc.z += v.z; acc.w += v.w;
        }
    }
    float dv = dinv[node];
    float4 r;
    r.x = acc.x * dv; r.y = acc.y * dv; r.z = acc.z * dv; r.w = acc.w * dv;
    if (BR) {
        float4 bv = *(const float4*)&b[lane * 4];
        r.x = fmaxf(r.x + bv.x, 0.f);
        r.y = fmaxf(r.y + bv.y, 0.f);
        r.z = fmaxf(r.z + bv.z, 0.f);
        r.w = fmaxf(r.w + bv.w, 0.f);
    }
    *(float4*)&out[(size_t)node * D + lane * 4] = r;
}

// out = Xin @ W (+epilogue). W fully resident in LDS. 256 threads, RTx4 tile/thread.
// MODE 0: out = relu(acc + bias[col])      (layer 1)
// MODE 1: out = acc * dinv[row]            (layers 2..4: pre-gather scale)
template <int K, int OUT, int RT, int MODE>
__launch_bounds__(256)
static __global__ void gemm_kernel(const float* __restrict__ Xin, const float* __restrict__ W,
                                   const float* __restrict__ bias, const float* __restrict__ dinv,
                                   float* __restrict__ out, int N) {
    constexpr int CT = OUT / 4;
    constexpr int RTH = 256 / CT;
    constexpr int RB = RTH * RT;
    constexpr int KP = K + 4;
    __shared__ float Wl[K * OUT];
    __shared__ float Xl[RB * KP];

    const int tid = threadIdx.x;
    const int row0 = blockIdx.x * RB;

    for (int idx = tid; idx < K * OUT / 4; idx += 256)
        ((float4*)Wl)[idx] = ((const float4*)W)[idx];

    constexpr int KC = K / 4;
    for (int idx = tid; idx < RB * KC; idx += 256) {
        int r = idx / KC;
        int kc = idx - r * KC;
        int g = row0 + r;
        float4 v = (g < N) ? ((const float4*)(Xin + (size_t)g * K))[kc]
                           : make_float4(0.f, 0.f, 0.f, 0.f);
        *(float4*)&Xl[r * KP + kc * 4] = v;
    }
    __syncthreads();

    const int tx = tid % CT, ty = tid / CT;
    const int col0 = tx * 4;
    float4 acc[RT];
#pragma unroll
    for (int i = 0; i < RT; i++) acc[i] = make_float4(0.f, 0.f, 0.f, 0.f);

#pragma unroll 4
    for (int k = 0; k < K; k += 4) {
        float4 w0 = *(float4*)&Wl[(k + 0) * OUT + col0];
        float4 w1 = *(float4*)&Wl[(k + 1) * OUT + col0];
        float4 w2 = *(float4*)&Wl[(k + 2) * OUT + col0];
        float4 w3 = *(float4*)&Wl[(k + 3) * OUT + col0];
#pragma unroll
        for (int i = 0; i < RT; i++) {
            float4 xv = *(float4*)&Xl[(ty * RT + i) * KP + k];
            acc[i].x += xv.x * w0.x + xv.y * w1.x + xv.z * w2.x + xv.w * w3.x;
            acc[i].y += xv.x * w0.y + xv.y * w1.y + xv.z * w2.y + xv.w * w3.y;
            acc[i].z += xv.x * w0.z + xv.y * w1.z + xv.z * w2.z + xv.w * w3.z;
            acc[i].w += xv.x * w0.w + xv.y * w1.w + xv.z * w2.w + xv.w * w3.w;
        }
    }

    if (MODE == 0) {
        float4 bv = *(const float4*)&bias[col0];
#pragma unroll
        for (int i = 0; i < RT; i++) {
            int g = row0 + ty * RT + i;
            if (g < N) {
                float4 r;
                r.x = fmaxf(acc[i].x + bv.x, 0.f);
                r.y = fmaxf(acc[i].y + bv.y, 0.f);
                r.z = fmaxf(acc[i].z + bv.z, 0.f);
                r.w = fmaxf(acc[i].w + bv.w, 0.f);
                *(float4*)&out[(size_t)g * OUT + col0] = r;
            }
        }
    } else {
#pragma unroll
        for (int i = 0; i < RT; i++) {
            int g = row0 + ty * RT + i;
            if (g < N) {
                float d = dinv[g];
                float4 r;
                r.x = acc[i].x * d; r.y = acc[i].y * d;
                r.z = acc[i].z * d; r.w = acc[i].w * d;
                *(float4*)&out[(size_t)g * OUT + col0] = r;
            }
        }
    }
}

static __global__ void pool_kernel(const float* __restrict__ h, const float* __restrict__ Wfc,
                                   const int* __restrict__ batch, float* __restrict__ psum,
                                   int* __restrict__ pcnt, int N) {
    __shared__ float wl[32];
    __shared__ float gsum[64];
    __shared__ int gcnt[64];
    __shared__ int sbase;
    int tid = threadIdx.x;
    if (tid < 32) wl[tid] = Wfc[tid];
    if (tid < 64) { gsum[tid] = 0.f; gcnt[tid] = 0; }
    if (tid == 0) sbase = batch[blockIdx.x * 256];
    __syncthreads();

    int n = blockIdx.x * 256 + tid;
    if (n < N) {
        const float4* hp = (const float4*)(h + (size_t)n * 32);
        float val = 0.f;
#pragma unroll
        for (int j = 0; j < 8; j++) {
            float4 hv = hp[j];
            val += hv.x * wl[j * 4 + 0] + hv.y * wl[j * 4 + 1] +
                   hv.z * wl[j * 4 + 2] + hv.w * wl[j * 4 + 3];
        }
        int g = batch[n];
        int rel = g - sbase;
        if ((unsigned)rel < 64u) {
            atomicAdd(&gsum[rel], val);
            atomicAdd(&gcnt[rel], 1);
        } else {
            unsafeAtomicAdd(&psum[g], val);
            atomicAdd(&pcnt[g], 1);
        }
    }
    __syncthreads();
    if (tid < 64 && gcnt[tid] > 0) {
        unsafeAtomicAdd(&psum[sbase + tid], gsum[tid]);
        atomicAdd(&pcnt[sbase + tid], gcnt[tid]);
    }
}

static __global__ void final_kernel(const float* __restrict__ psum, const int* __restrict__ pcnt,
                                    const float* __restrict__ bfc, float* __restrict__ out, int G) {
    int t = threadIdx.x;
    if (t < G) {
        float c = (float)pcnt[t];
        out[t] = psum[t] / fmaxf(c, 1.f) + bfc[0];
    }
}

extern "C" void kernel_launch(void* const* d_in, const int* in_sizes, int n_in,
                              void* d_out, int out_size, void* d_ws, size_t ws_size,
                              hipStream_t stream) {
    const float* x    = (const float*)d_in[0];
    const int*   ei   = (const int*)d_in[1];
    const int*   batch= (const int*)d_in[2];
    const float* W1   = (const float*)d_in[4];
    const float* b1   = (const float*)d_in[5];
    const float* W2   = (const float*)d_in[6];
    const float* b2   = (const float*)d_in[7];
    const float* W3   = (const float*)d_in[8];
    const float* b3   = (const float*)d_in[9];
    const float* W4   = (const float*)d_in[10];
    const float* b4   = (const float*)d_in[11];
    const float* Wfc  = (const float*)d_in[12];
    const float* bfc  = (const float*)d_in[13];
    float* out = (float*)d_out;

    const int N = in_sizes[0] / 64;
    const int E = in_sizes[1] / 2;
    const int G = out_size;
    const int* srcp = ei;
    const int* dstp = ei + E;

    // workspace layout (float-sized slots)
    float* wsf = (float*)d_ws;
    const size_t Npad = ((size_t)N + 1023) / 1024 * 1024;
    const size_t Epad = ((size_t)E + 1023) / 1024 * 1024;
    float* dinv   = wsf;                       // Npad
    int*   deg    = (int*)(wsf + Npad);        // Npad
    int*   rowptr = (int*)(wsf + 2 * Npad);    // Npad+1 (needs N+1)
    int*   fillc  = (int*)(wsf + 3 * Npad + 1024); // Npad
    int*   col    = (int*)(wsf + 4 * Npad + 1024); // Epad
    int*   bsum   = (int*)((float*)col + Epad);    // 1024
    float* psum   = (float*)bsum + 1024;       // 256
    int*   pcnt   = (int*)(psum + 256);        // 256
    float* T1     = psum + 1024;               // Npad*64
    float* T2     = T1 + Npad * 64;            // Npad*64
    float* H1     = T2 + Npad * 64;            // Npad*128

    const int gE   = (E + 255) / 256;
    const int gN   = (N + 255) / 256;
    const int gN16 = (N * 16 + 255) / 256;
    const int nb   = (N + 255) / 256;          // number of block sums (<=512)

    hipMemsetAsync(deg, 0, sizeof(int) * N, stream);
    hipMemsetAsync(psum, 0, 512 * sizeof(float), stream);

    // ---- degree + CSR build (by dst, col = src)
    deg_kernel<<<gE, 256, 0, stream>>>(dstp, deg, E);
    dinv_kernel<<<gN, 256, 0, stream>>>(deg, dinv, N);
    blocksum_kernel<<<nb, 256, 0, stream>>>(deg, bsum, N);
    scanb_kernel<<<1, 512, 0, stream>>>(bsum, nb);
    scanc_kernel<<<nb, 256, 0, stream>>>(deg, bsum, rowptr, fillc, N, E);
    fill_kernel<<<gE, 256, 0, stream>>>(srcp, dstp, fillc, col, E);

    // ---- layer 1: aggregate X (dim 64) first, then GEMM 64->128 + bias + relu
    scale_kernel<<<gN16, 256, 0, stream>>>(x, dinv, T1, N);
    gather_kernel<16, false><<<(N + 15) / 16, 256, 0, stream>>>(T1, rowptr, col, dinv, nullptr, T2, N);
    gemm_kernel<64, 128, 4, 0><<<(N + 31) / 32, 256, 0, stream>>>(T2, W1, b1, nullptr, H1, N);

    // ---- layer 2: GEMM 128->64 (scale by dinv), gather(bias+relu)
    gemm_kernel<128, 64, 2, 1><<<(N + 31) / 32, 256, 0, stream>>>(H1, W2, nullptr, dinv, T1, N);
    gather_kernel<16, true><<<(N + 15) / 16, 256, 0, stream>>>(T1, rowptr, col, dinv, b2, T2, N);

    // ---- layer 3: GEMM 64->64
    gemm_kernel<64, 64, 4, 1><<<(N + 63) / 64, 256, 0, stream>>>(T2, W3, nullptr, dinv, T1, N);
    gather_kernel<16, true><<<(N + 15) / 16, 256, 0, stream>>>(T1, rowptr, col, dinv, b3, T2, N);

    // ---- layer 4: GEMM 64->32
    gemm_kernel<64, 32, 4, 1><<<(N + 127) / 128, 256, 0, stream>>>(T2, W4, nullptr, dinv, T1, N);
    gather_kernel<8, true><<<(N + 31) / 32, 256, 0, stream>>>(T1, rowptr, col, dinv, b4, T2, N);

    // ---- pool + fc
    pool_kernel<<<gN, 256, 0, stream>>>(T2, Wfc, batch, psum, pcnt, N);
    final_kernel<<<1, 256, 0, stream>>>(psum, pcnt, bfc, out, G);
}

// Round 3
// 537.216 us; speedup vs baseline: 9.4062x; 1.1869x over previous
//
#include <hip/hip_runtime.h>
#include <cstdint>
#include <cstddef>

// ---------------------------------------------------------------------------
// GCN regression, fp32. Round 3:
//  - CSR build via write-local two-level bucketing (98 buckets x 1024 nodes):
//      bhist -> bscan -> bin (per-block run reservation, full-line writes)
//      -> group (per-bucket LDS count/scan -> rowptr, dinv, streaming col).
//    Kills fill_kernel's 105MB partial-line write traffic.
//  - gather inner loop fully unrolled (16 independent loads in flight).
// ---------------------------------------------------------------------------

#define BKT_LG 10
#define BKT_SZ 1024
#define BIN_CHUNK 16384

// ---- bucket histogram: bcnt[b] = #edges with dst in bucket b
static __global__ void bhist_kernel(const int* __restrict__ dst, int* __restrict__ bcnt,
                                    int E, int NB) {
    __shared__ int h[128];
    for (int i = threadIdx.x; i < NB; i += 256) h[i] = 0;
    __syncthreads();
    for (int t = blockIdx.x * 256 + threadIdx.x; t < E; t += gridDim.x * 256)
        atomicAdd(&h[dst[t] >> BKT_LG], 1);
    __syncthreads();
    for (int i = threadIdx.x; i < NB; i += 256)
        if (h[i]) atomicAdd(&bcnt[i], h[i]);
}

// ---- exclusive scan of bcnt -> base (NB+1), bfill = base  (single block)
static __global__ void bscan_kernel(const int* __restrict__ bcnt, int* __restrict__ base,
                                    int* __restrict__ bfill, int NB, int E) {
    __shared__ int s[128];
    int t = threadIdx.x;
    int v = (t < NB) ? bcnt[t] : 0;
    s[t] = v;
    __syncthreads();
    for (int off = 1; off < 128; off <<= 1) {
        int u = (t >= off) ? s[t - off] : 0;
        __syncthreads();
        s[t] += u;
        __syncthreads();
    }
    if (t < NB) { base[t] = s[t] - v; bfill[t] = s[t] - v; }
    if (t == 0) base[NB] = E;
}

// ---- bin edges into bucket-contiguous runs. Each block: LDS hist of its chunk,
//      one global atomic per bucket to reserve a run, then scatter into the run.
__launch_bounds__(256)
static __global__ void bin_kernel(const int* __restrict__ src, const int* __restrict__ dst,
                                  int* __restrict__ bfill, unsigned* __restrict__ binned,
                                  int E, int NB) {
    __shared__ int h[128];
    __shared__ int res[128];
    const int beg = blockIdx.x * BIN_CHUNK;
    const int ce = min(BIN_CHUNK, E - beg);
    for (int i = threadIdx.x; i < NB; i += 256) h[i] = 0;
    __syncthreads();
    for (int i = threadIdx.x; i < ce; i += 256)
        atomicAdd(&h[dst[beg + i] >> BKT_LG], 1);
    __syncthreads();
    for (int i = threadIdx.x; i < NB; i += 256) {
        res[i] = h[i] ? atomicAdd(&bfill[i], h[i]) : 0;
        h[i] = 0;
    }
    __syncthreads();
    for (int i = threadIdx.x; i < ce; i += 256) {
        int d = dst[beg + i];
        int b = d >> BKT_LG;
        int p = res[b] + atomicAdd(&h[b], 1);
        binned[p] = ((unsigned)src[beg + i] << BKT_LG) | (unsigned)(d & (BKT_SZ - 1));
    }
}

// ---- per-bucket: count per node, scan, emit rowptr/dinv, group col (streaming)
__launch_bounds__(256)
static __global__ void group_kernel(const unsigned* __restrict__ binned, const int* __restrict__ base,
                                    int* __restrict__ rowptr, int* __restrict__ col,
                                    float* __restrict__ dinv, int N, int E) {
    __shared__ int cnt[BKT_SZ];
    __shared__ int ex[BKT_SZ];
    __shared__ int ps[256];
    const int tid = threadIdx.x;
    const int b = blockIdx.x;
    const int node0 = b << BKT_LG;
    const int nn = min(BKT_SZ, N - node0);
    const int beg = base[b], end = base[b + 1];

    for (int i = tid; i < BKT_SZ; i += 256) cnt[i] = 0;
    __syncthreads();
    for (int i = beg + tid; i < end; i += 256)
        atomicAdd(&cnt[binned[i] & (BKT_SZ - 1)], 1);
    __syncthreads();

    // exclusive scan of cnt[0..1024): 4 serial per thread + block scan of partials
    const int b4 = tid * 4;
    int c0 = cnt[b4], c1 = cnt[b4 + 1], c2 = cnt[b4 + 2], c3 = cnt[b4 + 3];
    int s01 = c0 + c1;
    int s = s01 + c2 + c3;
    ps[tid] = s;
    __syncthreads();
    for (int off = 1; off < 256; off <<= 1) {
        int u = (tid >= off) ? ps[tid - off] : 0;
        __syncthreads();
        ps[tid] += u;
        __syncthreads();
    }
    int excl = ps[tid] - s;
    ex[b4]     = excl;
    ex[b4 + 1] = excl + c0;
    ex[b4 + 2] = excl + s01;
    ex[b4 + 3] = excl + s01 + c2;
    __syncthreads();

    for (int i = tid; i < nn; i += 256) {
        rowptr[node0 + i] = beg + ex[i];
        dinv[node0 + i] = rsqrtf((float)cnt[i] + 1.0f);
    }
    if (b == 0 && tid == 0) rowptr[N] = E;
    __syncthreads();

    // fill: bump ex atomically; col writes contiguous within [beg,end)
    for (int i = beg + tid; i < end; i += 256) {
        unsigned v = binned[i];
        int dl = v & (BKT_SZ - 1);
        int p = atomicAdd(&ex[dl], 1);
        col[beg + p] = (int)(v >> BKT_LG);
    }
}

// o[row] = x[row] * dinv[row], dim 64
static __global__ void scale_kernel(const float* __restrict__ x, const float* __restrict__ dinv,
                                    float* __restrict__ o, int N) {
    int t = blockIdx.x * 256 + threadIdx.x;
    if (t >= N * 16) return;
    int row = t >> 4;
    int c = (t & 15) * 4;
    float d = dinv[row];
    float4 v = *(const float4*)&x[(size_t)row * 64 + c];
    v.x *= d; v.y *= d; v.z *= d; v.w *= d;
    *(float4*)&o[(size_t)row * 64 + c] = v;
}

// out[d] = dinv[d]*(sum_{s in row d} hs[s] + hs[d])  [+bias, relu if BR]
// D4 threads per node; chunk of D4 edges fully unrolled -> D4 loads in flight.
template <int D4, bool BR>
__launch_bounds__(256)
static __global__ void gather_kernel(const float* __restrict__ hs, const int* __restrict__ rowptr,
                                     const int* __restrict__ col, const float* __restrict__ dinv,
                                     const float* __restrict__ b, float* __restrict__ out, int N) {
    constexpr int D = D4 * 4;
    constexpr int NPB = 256 / D4;
    constexpr int LG = (D4 == 16) ? 4 : 3;
    const int lane = threadIdx.x & (D4 - 1);
    const int node = blockIdx.x * NPB + (threadIdx.x >> LG);
    if (node >= N) return;
    const int beg = rowptr[node];
    const int end = rowptr[node + 1];
    float4 acc = *(const float4*)&hs[(size_t)node * D + lane * 4];  // self loop
    float4 acc2 = make_float4(0.f, 0.f, 0.f, 0.f);
    int e = beg;
    for (; e + D4 <= end; e += D4) {
        int myc = col[e + lane];
#pragma unroll
        for (int j = 0; j < D4; j += 2) {
            int s0 = __shfl(myc, j, D4);
            int s1 = __shfl(myc, j + 1, D4);
            float4 v0 = *(const float4*)&hs[(size_t)s0 * D + lane * 4];
            float4 v1 = *(const float4*)&hs[(size_t)s1 * D + lane * 4];
            acc.x += v0.x; acc.y += v0.y; acc.z += v0.z; acc.w += v0.w;
            acc2.x += v1.x; acc2.y += v1.y; acc2.z += v1.z; acc2.w += v1.w;
        }
    }
    if (e < end) {
        int m = end - e;
        int myc = (e + lane < end) ? col[e + lane] : 0;
        for (int j = 0; j < m; ++j) {
            int s = __shfl(myc, j, D4);
            float4 v = *(const float4*)&hs[(size_t)s * D + lane * 4];
            acc.x += v.x; acc.y += v.y; acc.z += v.z; acc.w += v.w;
        }
    }
    acc.x += acc2.x; acc.y += acc2.y; acc.z += acc2.z; acc.w += acc2.w;
    float dv = dinv[node];
    float4 r;
    r.x = acc.x * dv; r.y = acc.y * dv; r.z = acc.z * dv; r.w = acc.w * dv;
    if (BR) {
        float4 bv = *(const float4*)&b[lane * 4];
        r.x = fmaxf(r.x + bv.x, 0.f);
        r.y = fmaxf(r.y + bv.y, 0.f);
        r.z = fmaxf(r.z + bv.z, 0.f);
        r.w = fmaxf(r.w + bv.w, 0.f);
    }
    *(float4*)&out[(size_t)node * D + lane * 4] = r;
}

// out = Xin @ W (+epilogue). W fully resident in LDS.
// MODE 0: out = relu(acc + bias[col]);  MODE 1: out = acc * dinv[row]
template <int K, int OUT, int RT, int MODE>
__launch_bounds__(256)
static __global__ void gemm_kernel(const float* __restrict__ Xin, const float* __restrict__ W,
                                   const float* __restrict__ bias, const float* __restrict__ dinv,
                                   float* __restrict__ out, int N) {
    constexpr int CT = OUT / 4;
    constexpr int RTH = 256 / CT;
    constexpr int RB = RTH * RT;
    constexpr int KP = K + 4;
    __shared__ float Wl[K * OUT];
    __shared__ float Xl[RB * KP];

    const int tid = threadIdx.x;
    const int row0 = blockIdx.x * RB;

    for (int idx = tid; idx < K * OUT / 4; idx += 256)
        ((float4*)Wl)[idx] = ((const float4*)W)[idx];

    constexpr int KC = K / 4;
    for (int idx = tid; idx < RB * KC; idx += 256) {
        int r = idx / KC;
        int kc = idx - r * KC;
        int g = row0 + r;
        float4 v = (g < N) ? ((const float4*)(Xin + (size_t)g * K))[kc]
                           : make_float4(0.f, 0.f, 0.f, 0.f);
        *(float4*)&Xl[r * KP + kc * 4] = v;
    }
    __syncthreads();

    const int tx = tid % CT, ty = tid / CT;
    const int col0 = tx * 4;
    float4 acc[RT];
#pragma unroll
    for (int i = 0; i < RT; i++) acc[i] = make_float4(0.f, 0.f, 0.f, 0.f);

#pragma unroll 4
    for (int k = 0; k < K; k += 4) {
        float4 w0 = *(float4*)&Wl[(k + 0) * OUT + col0];
        float4 w1 = *(float4*)&Wl[(k + 1) * OUT + col0];
        float4 w2 = *(float4*)&Wl[(k + 2) * OUT + col0];
        float4 w3 = *(float4*)&Wl[(k + 3) * OUT + col0];
#pragma unroll
        for (int i = 0; i < RT; i++) {
            float4 xv = *(float4*)&Xl[(ty * RT + i) * KP + k];
            acc[i].x += xv.x * w0.x + xv.y * w1.x + xv.z * w2.x + xv.w * w3.x;
            acc[i].y += xv.x * w0.y + xv.y * w1.y + xv.z * w2.y + xv.w * w3.y;
            acc[i].z += xv.x * w0.z + xv.y * w1.z + xv.z * w2.z + xv.w * w3.z;
            acc[i].w += xv.x * w0.w + xv.y * w1.w + xv.z * w2.w + xv.w * w3.w;
        }
    }

    if (MODE == 0) {
        float4 bv = *(const float4*)&bias[col0];
#pragma unroll
        for (int i = 0; i < RT; i++) {
            int g = row0 + ty * RT + i;
            if (g < N) {
                float4 r;
                r.x = fmaxf(acc[i].x + bv.x, 0.f);
                r.y = fmaxf(acc[i].y + bv.y, 0.f);
                r.z = fmaxf(acc[i].z + bv.z, 0.f);
                r.w = fmaxf(acc[i].w + bv.w, 0.f);
                *(float4*)&out[(size_t)g * OUT + col0] = r;
            }
        }
    } else {
#pragma unroll
        for (int i = 0; i < RT; i++) {
            int g = row0 + ty * RT + i;
            if (g < N) {
                float d = dinv[g];
                float4 r;
                r.x = acc[i].x * d; r.y = acc[i].y * d;
                r.z = acc[i].z * d; r.w = acc[i].w * d;
                *(float4*)&out[(size_t)g * OUT + col0] = r;
            }
        }
    }
}

static __global__ void pool_kernel(const float* __restrict__ h, const float* __restrict__ Wfc,
                                   const int* __restrict__ batch, float* __restrict__ psum,
                                   int* __restrict__ pcnt, int N) {
    __shared__ float wl[32];
    __shared__ float gsum[64];
    __shared__ int gcnt[64];
    __shared__ int sbase;
    int tid = threadIdx.x;
    if (tid < 32) wl[tid] = Wfc[tid];
    if (tid < 64) { gsum[tid] = 0.f; gcnt[tid] = 0; }
    if (tid == 0) sbase = batch[blockIdx.x * 256];
    __syncthreads();

    int n = blockIdx.x * 256 + tid;
    if (n < N) {
        const float4* hp = (const float4*)(h + (size_t)n * 32);
        float val = 0.f;
#pragma unroll
        for (int j = 0; j < 8; j++) {
            float4 hv = hp[j];
            val += hv.x * wl[j * 4 + 0] + hv.y * wl[j * 4 + 1] +
                   hv.z * wl[j * 4 + 2] + hv.w * wl[j * 4 + 3];
        }
        int g = batch[n];
        int rel = g - sbase;
        if ((unsigned)rel < 64u) {
            atomicAdd(&gsum[rel], val);
            atomicAdd(&gcnt[rel], 1);
        } else {
            unsafeAtomicAdd(&psum[g], val);
            atomicAdd(&pcnt[g], 1);
        }
    }
    __syncthreads();
    if (tid < 64 && gcnt[tid] > 0) {
        unsafeAtomicAdd(&psum[sbase + tid], gsum[tid]);
        atomicAdd(&pcnt[sbase + tid], gcnt[tid]);
    }
}

static __global__ void final_kernel(const float* __restrict__ psum, const int* __restrict__ pcnt,
                                    const float* __restrict__ bfc, float* __restrict__ out, int G) {
    int t = threadIdx.x;
    if (t < G) {
        float c = (float)pcnt[t];
        out[t] = psum[t] / fmaxf(c, 1.f) + bfc[0];
    }
}

extern "C" void kernel_launch(void* const* d_in, const int* in_sizes, int n_in,
                              void* d_out, int out_size, void* d_ws, size_t ws_size,
                              hipStream_t stream) {
    const float* x    = (const float*)d_in[0];
    const int*   ei   = (const int*)d_in[1];
    const int*   batch= (const int*)d_in[2];
    const float* W1   = (const float*)d_in[4];
    const float* b1   = (const float*)d_in[5];
    const float* W2   = (const float*)d_in[6];
    const float* b2   = (const float*)d_in[7];
    const float* W3   = (const float*)d_in[8];
    const float* b3   = (const float*)d_in[9];
    const float* W4   = (const float*)d_in[10];
    const float* b4   = (const float*)d_in[11];
    const float* Wfc  = (const float*)d_in[12];
    const float* bfc  = (const float*)d_in[13];
    float* out = (float*)d_out;

    const int N = in_sizes[0] / 64;
    const int E = in_sizes[1] / 2;
    const int G = out_size;
    const int* srcp = ei;
    const int* dstp = ei + E;
    const int NB = (N + BKT_SZ - 1) >> BKT_LG;   // 98 for N=100k

    // workspace layout (float-sized slots)
    float* wsf = (float*)d_ws;
    const size_t Npad = ((size_t)N + 1023) / 1024 * 1024;
    const size_t Epad = ((size_t)E + 1023) / 1024 * 1024;
    float*    dinv   = wsf;                            // Npad
    int*      rowptr = (int*)(wsf + Npad);             // Npad + 1024
    int*      col    = (int*)(wsf + 2 * Npad + 1024);  // Epad
    unsigned* binned = (unsigned*)((float*)col + Epad);// Epad
    int*      bcnt   = (int*)((float*)binned + Epad);  // 256
    int*      base   = bcnt + 256;                     // 256
    int*      bfill  = base + 256;                     // 256
    float*    psum   = (float*)(bfill + 256);          // 256
    int*      pcnt   = (int*)(psum + 256);             // 256
    float*    T1     = psum + 1024;                    // Npad*64
    float*    T2     = T1 + Npad * 64;                 // Npad*64
    float*    H1     = T2 + Npad * 64;                 // Npad*128

    const int gN   = (N + 255) / 256;
    const int gN16 = (N * 16 + 255) / 256;
    const int nbin = (E + BIN_CHUNK - 1) / BIN_CHUNK;

    hipMemsetAsync(bcnt, 0, 256 * sizeof(int), stream);
    hipMemsetAsync(psum, 0, 512 * sizeof(float), stream);

    // ---- CSR build (by dst, col = src) + dinv
    bhist_kernel<<<256, 256, 0, stream>>>(dstp, bcnt, E, NB);
    bscan_kernel<<<1, 128, 0, stream>>>(bcnt, base, bfill, NB, E);
    bin_kernel<<<nbin, 256, 0, stream>>>(srcp, dstp, bfill, binned, E, NB);
    group_kernel<<<NB, 256, 0, stream>>>(binned, base, rowptr, col, dinv, N, E);

    // ---- layer 1: aggregate X (dim 64) first, then GEMM 64->128 + bias + relu
    scale_kernel<<<gN16, 256, 0, stream>>>(x, dinv, T1, N);
    gather_kernel<16, false><<<(N + 15) / 16, 256, 0, stream>>>(T1, rowptr, col, dinv, nullptr, T2, N);
    gemm_kernel<64, 128, 4, 0><<<(N + 31) / 32, 256, 0, stream>>>(T2, W1, b1, nullptr, H1, N);

    // ---- layer 2: GEMM 128->64 (scale by dinv), gather(bias+relu)
    gemm_kernel<128, 64, 2, 1><<<(N + 31) / 32, 256, 0, stream>>>(H1, W2, nullptr, dinv, T1, N);
    gather_kernel<16, true><<<(N + 15) / 16, 256, 0, stream>>>(T1, rowptr, col, dinv, b2, T2, N);

    // ---- layer 3: GEMM 64->64
    gemm_kernel<64, 64, 4, 1><<<(N + 63) / 64, 256, 0, stream>>>(T2, W3, nullptr, dinv, T1, N);
    gather_kernel<16, true><<<(N + 15) / 16, 256, 0, stream>>>(T1, rowptr, col, dinv, b3, T2, N);

    // ---- layer 4: GEMM 64->32
    gemm_kernel<64, 32, 4, 1><<<(N + 127) / 128, 256, 0, stream>>>(T2, W4, nullptr, dinv, T1, N);
    gather_kernel<8, true><<<(N + 31) / 32, 256, 0, stream>>>(T1, rowptr, col, dinv, b4, T2, N);

    // ---- pool + fc
    pool_kernel<<<gN, 256, 0, stream>>>(T2, Wfc, batch, psum, pcnt, N);
    final_kernel<<<1, 256, 0, stream>>>(psum, pcnt, bfc, out, G);
}

// Round 4
// 512.657 us; speedup vs baseline: 9.8568x; 1.0479x over previous
//
#include <hip/hip_runtime.h>
#include <cstdint>
#include <cstddef>

// ---------------------------------------------------------------------------
// GCN regression, fp32. Round 4: bin_kernel BIN_CHUNK 16384 -> 2048.
//   R3 profile: bin_kernel 70us at 3% occupancy (98 blocks on 256 CUs),
//   VALUBusy 0.85%, HBM 2.3% -> pure under-parallelization. 782 blocks now.
// ---------------------------------------------------------------------------

#define BKT_LG 10
#define BKT_SZ 1024
#define BIN_CHUNK 2048

// ---- bucket histogram: bcnt[b] = #edges with dst in bucket b
static __global__ void bhist_kernel(const int* __restrict__ dst, int* __restrict__ bcnt,
                                    int E, int NB) {
    __shared__ int h[128];
    for (int i = threadIdx.x; i < NB; i += 256) h[i] = 0;
    __syncthreads();
    for (int t = blockIdx.x * 256 + threadIdx.x; t < E; t += gridDim.x * 256)
        atomicAdd(&h[dst[t] >> BKT_LG], 1);
    __syncthreads();
    for (int i = threadIdx.x; i < NB; i += 256)
        if (h[i]) atomicAdd(&bcnt[i], h[i]);
}

// ---- exclusive scan of bcnt -> base (NB+1), bfill = base  (single block)
static __global__ void bscan_kernel(const int* __restrict__ bcnt, int* __restrict__ base,
                                    int* __restrict__ bfill, int NB, int E) {
    __shared__ int s[128];
    int t = threadIdx.x;
    int v = (t < NB) ? bcnt[t] : 0;
    s[t] = v;
    __syncthreads();
    for (int off = 1; off < 128; off <<= 1) {
        int u = (t >= off) ? s[t - off] : 0;
        __syncthreads();
        s[t] += u;
        __syncthreads();
    }
    if (t < NB) { base[t] = s[t] - v; bfill[t] = s[t] - v; }
    if (t == 0) base[NB] = E;
}

// ---- bin edges into bucket-contiguous runs. Each block: LDS hist of its chunk,
//      one global atomic per bucket to reserve a run, then scatter into the run.
__launch_bounds__(256)
static __global__ void bin_kernel(const int* __restrict__ src, const int* __restrict__ dst,
                                  int* __restrict__ bfill, unsigned* __restrict__ binned,
                                  int E, int NB) {
    __shared__ int h[128];
    __shared__ int res[128];
    const int beg = blockIdx.x * BIN_CHUNK;
    const int ce = min(BIN_CHUNK, E - beg);
    for (int i = threadIdx.x; i < NB; i += 256) h[i] = 0;
    __syncthreads();
    for (int i = threadIdx.x; i < ce; i += 256)
        atomicAdd(&h[dst[beg + i] >> BKT_LG], 1);
    __syncthreads();
    for (int i = threadIdx.x; i < NB; i += 256) {
        res[i] = h[i] ? atomicAdd(&bfill[i], h[i]) : 0;
        h[i] = 0;
    }
    __syncthreads();
    for (int i = threadIdx.x; i < ce; i += 256) {
        int d = dst[beg + i];
        int b = d >> BKT_LG;
        int p = res[b] + atomicAdd(&h[b], 1);
        binned[p] = ((unsigned)src[beg + i] << BKT_LG) | (unsigned)(d & (BKT_SZ - 1));
    }
}

// ---- per-bucket: count per node, scan, emit rowptr/dinv, group col (streaming)
__launch_bounds__(256)
static __global__ void group_kernel(const unsigned* __restrict__ binned, const int* __restrict__ base,
                                    int* __restrict__ rowptr, int* __restrict__ col,
                                    float* __restrict__ dinv, int N, int E) {
    __shared__ int cnt[BKT_SZ];
    __shared__ int ex[BKT_SZ];
    __shared__ int ps[256];
    const int tid = threadIdx.x;
    const int b = blockIdx.x;
    const int node0 = b << BKT_LG;
    const int nn = min(BKT_SZ, N - node0);
    const int beg = base[b], end = base[b + 1];

    for (int i = tid; i < BKT_SZ; i += 256) cnt[i] = 0;
    __syncthreads();
    for (int i = beg + tid; i < end; i += 256)
        atomicAdd(&cnt[binned[i] & (BKT_SZ - 1)], 1);
    __syncthreads();

    // exclusive scan of cnt[0..1024): 4 serial per thread + block scan of partials
    const int b4 = tid * 4;
    int c0 = cnt[b4], c1 = cnt[b4 + 1], c2 = cnt[b4 + 2], c3 = cnt[b4 + 3];
    int s01 = c0 + c1;
    int s = s01 + c2 + c3;
    ps[tid] = s;
    __syncthreads();
    for (int off = 1; off < 256; off <<= 1) {
        int u = (tid >= off) ? ps[tid - off] : 0;
        __syncthreads();
        ps[tid] += u;
        __syncthreads();
    }
    int excl = ps[tid] - s;
    ex[b4]     = excl;
    ex[b4 + 1] = excl + c0;
    ex[b4 + 2] = excl + s01;
    ex[b4 + 3] = excl + s01 + c2;
    __syncthreads();

    for (int i = tid; i < nn; i += 256) {
        rowptr[node0 + i] = beg + ex[i];
        dinv[node0 + i] = rsqrtf((float)cnt[i] + 1.0f);
    }
    if (b == 0 && tid == 0) rowptr[N] = E;
    __syncthreads();

    // fill: bump ex atomically; col writes contiguous within [beg,end)
    for (int i = beg + tid; i < end; i += 256) {
        unsigned v = binned[i];
        int dl = v & (BKT_SZ - 1);
        int p = atomicAdd(&ex[dl], 1);
        col[beg + p] = (int)(v >> BKT_LG);
    }
}

// o[row] = x[row] * dinv[row], dim 64
static __global__ void scale_kernel(const float* __restrict__ x, const float* __restrict__ dinv,
                                    float* __restrict__ o, int N) {
    int t = blockIdx.x * 256 + threadIdx.x;
    if (t >= N * 16) return;
    int row = t >> 4;
    int c = (t & 15) * 4;
    float d = dinv[row];
    float4 v = *(const float4*)&x[(size_t)row * 64 + c];
    v.x *= d; v.y *= d; v.z *= d; v.w *= d;
    *(float4*)&o[(size_t)row * 64 + c] = v;
}

// out[d] = dinv[d]*(sum_{s in row d} hs[s] + hs[d])  [+bias, relu if BR]
// D4 threads per node; chunk of D4 edges fully unrolled -> D4 loads in flight.
template <int D4, bool BR>
__launch_bounds__(256)
static __global__ void gather_kernel(const float* __restrict__ hs, const int* __restrict__ rowptr,
                                     const int* __restrict__ col, const float* __restrict__ dinv,
                                     const float* __restrict__ b, float* __restrict__ out, int N) {
    constexpr int D = D4 * 4;
    constexpr int NPB = 256 / D4;
    constexpr int LG = (D4 == 16) ? 4 : 3;
    const int lane = threadIdx.x & (D4 - 1);
    const int node = blockIdx.x * NPB + (threadIdx.x >> LG);
    if (node >= N) return;
    const int beg = rowptr[node];
    const int end = rowptr[node + 1];
    float4 acc = *(const float4*)&hs[(size_t)node * D + lane * 4];  // self loop
    float4 acc2 = make_float4(0.f, 0.f, 0.f, 0.f);
    int e = beg;
    for (; e + D4 <= end; e += D4) {
        int myc = col[e + lane];
#pragma unroll
        for (int j = 0; j < D4; j += 2) {
            int s0 = __shfl(myc, j, D4);
            int s1 = __shfl(myc, j + 1, D4);
            float4 v0 = *(const float4*)&hs[(size_t)s0 * D + lane * 4];
            float4 v1 = *(const float4*)&hs[(size_t)s1 * D + lane * 4];
            acc.x += v0.x; acc.y += v0.y; acc.z += v0.z; acc.w += v0.w;
            acc2.x += v1.x; acc2.y += v1.y; acc2.z += v1.z; acc2.w += v1.w;
        }
    }
    if (e < end) {
        int m = end - e;
        int myc = (e + lane < end) ? col[e + lane] : 0;
        for (int j = 0; j < m; ++j) {
            int s = __shfl(myc, j, D4);
            float4 v = *(const float4*)&hs[(size_t)s * D + lane * 4];
            acc.x += v.x; acc.y += v.y; acc.z += v.z; acc.w += v.w;
        }
    }
    acc.x += acc2.x; acc.y += acc2.y; acc.z += acc2.z; acc.w += acc2.w;
    float dv = dinv[node];
    float4 r;
    r.x = acc.x * dv; r.y = acc.y * dv; r.z = acc.z * dv; r.w = acc.w * dv;
    if (BR) {
        float4 bv = *(const float4*)&b[lane * 4];
        r.x = fmaxf(r.x + bv.x, 0.f);
        r.y = fmaxf(r.y + bv.y, 0.f);
        r.z = fmaxf(r.z + bv.z, 0.f);
        r.w = fmaxf(r.w + bv.w, 0.f);
    }
    *(float4*)&out[(size_t)node * D + lane * 4] = r;
}

// out = Xin @ W (+epilogue). W fully resident in LDS.
// MODE 0: out = relu(acc + bias[col]);  MODE 1: out = acc * dinv[row]
template <int K, int OUT, int RT, int MODE>
__launch_bounds__(256)
static __global__ void gemm_kernel(const float* __restrict__ Xin, const float* __restrict__ W,
                                   const float* __restrict__ bias, const float* __restrict__ dinv,
                                   float* __restrict__ out, int N) {
    constexpr int CT = OUT / 4;
    constexpr int RTH = 256 / CT;
    constexpr int RB = RTH * RT;
    constexpr int KP = K + 4;
    __shared__ float Wl[K * OUT];
    __shared__ float Xl[RB * KP];

    const int tid = threadIdx.x;
    const int row0 = blockIdx.x * RB;

    for (int idx = tid; idx < K * OUT / 4; idx += 256)
        ((float4*)Wl)[idx] = ((const float4*)W)[idx];

    constexpr int KC = K / 4;
    for (int idx = tid; idx < RB * KC; idx += 256) {
        int r = idx / KC;
        int kc = idx - r * KC;
        int g = row0 + r;
        float4 v = (g < N) ? ((const float4*)(Xin + (size_t)g * K))[kc]
                           : make_float4(0.f, 0.f, 0.f, 0.f);
        *(float4*)&Xl[r * KP + kc * 4] = v;
    }
    __syncthreads();

    const int tx = tid % CT, ty = tid / CT;
    const int col0 = tx * 4;
    float4 acc[RT];
#pragma unroll
    for (int i = 0; i < RT; i++) acc[i] = make_float4(0.f, 0.f, 0.f, 0.f);

#pragma unroll 4
    for (int k = 0; k < K; k += 4) {
        float4 w0 = *(float4*)&Wl[(k + 0) * OUT + col0];
        float4 w1 = *(float4*)&Wl[(k + 1) * OUT + col0];
        float4 w2 = *(float4*)&Wl[(k + 2) * OUT + col0];
        float4 w3 = *(float4*)&Wl[(k + 3) * OUT + col0];
#pragma unroll
        for (int i = 0; i < RT; i++) {
            float4 xv = *(float4*)&Xl[(ty * RT + i) * KP + k];
            acc[i].x += xv.x * w0.x + xv.y * w1.x + xv.z * w2.x + xv.w * w3.x;
            acc[i].y += xv.x * w0.y + xv.y * w1.y + xv.z * w2.y + xv.w * w3.y;
            acc[i].z += xv.x * w0.z + xv.y * w1.z + xv.z * w2.z + xv.w * w3.z;
            acc[i].w += xv.x * w0.w + xv.y * w1.w + xv.z * w2.w + xv.w * w3.w;
        }
    }

    if (MODE == 0) {
        float4 bv = *(const float4*)&bias[col0];
#pragma unroll
        for (int i = 0; i < RT; i++) {
            int g = row0 + ty * RT + i;
            if (g < N) {
                float4 r;
                r.x = fmaxf(acc[i].x + bv.x, 0.f);
                r.y = fmaxf(acc[i].y + bv.y, 0.f);
                r.z = fmaxf(acc[i].z + bv.z, 0.f);
                r.w = fmaxf(acc[i].w + bv.w, 0.f);
                *(float4*)&out[(size_t)g * OUT + col0] = r;
            }
        }
    } else {
#pragma unroll
        for (int i = 0; i < RT; i++) {
            int g = row0 + ty * RT + i;
            if (g < N) {
                float d = dinv[g];
                float4 r;
                r.x = acc[i].x * d; r.y = acc[i].y * d;
                r.z = acc[i].z * d; r.w = acc[i].w * d;
                *(float4*)&out[(size_t)g * OUT + col0] = r;
            }
        }
    }
}

static __global__ void pool_kernel(const float* __restrict__ h, const float* __restrict__ Wfc,
                                   const int* __restrict__ batch, float* __restrict__ psum,
                                   int* __restrict__ pcnt, int N) {
    __shared__ float wl[32];
    __shared__ float gsum[64];
    __shared__ int gcnt[64];
    __shared__ int sbase;
    int tid = threadIdx.x;
    if (tid < 32) wl[tid] = Wfc[tid];
    if (tid < 64) { gsum[tid] = 0.f; gcnt[tid] = 0; }
    if (tid == 0) sbase = batch[blockIdx.x * 256];
    __syncthreads();

    int n = blockIdx.x * 256 + tid;
    if (n < N) {
        const float4* hp = (const float4*)(h + (size_t)n * 32);
        float val = 0.f;
#pragma unroll
        for (int j = 0; j < 8; j++) {
            float4 hv = hp[j];
            val += hv.x * wl[j * 4 + 0] + hv.y * wl[j * 4 + 1] +
                   hv.z * wl[j * 4 + 2] + hv.w * wl[j * 4 + 3];
        }
        int g = batch[n];
        int rel = g - sbase;
        if ((unsigned)rel < 64u) {
            atomicAdd(&gsum[rel], val);
            atomicAdd(&gcnt[rel], 1);
        } else {
            unsafeAtomicAdd(&psum[g], val);
            atomicAdd(&pcnt[g], 1);
        }
    }
    __syncthreads();
    if (tid < 64 && gcnt[tid] > 0) {
        unsafeAtomicAdd(&psum[sbase + tid], gsum[tid]);
        atomicAdd(&pcnt[sbase + tid], gcnt[tid]);
    }
}

static __global__ void final_kernel(const float* __restrict__ psum, const int* __restrict__ pcnt,
                                    const float* __restrict__ bfc, float* __restrict__ out, int G) {
    int t = threadIdx.x;
    if (t < G) {
        float c = (float)pcnt[t];
        out[t] = psum[t] / fmaxf(c, 1.f) + bfc[0];
    }
}

extern "C" void kernel_launch(void* const* d_in, const int* in_sizes, int n_in,
                              void* d_out, int out_size, void* d_ws, size_t ws_size,
                              hipStream_t stream) {
    const float* x    = (const float*)d_in[0];
    const int*   ei   = (const int*)d_in[1];
    const int*   batch= (const int*)d_in[2];
    const float* W1   = (const float*)d_in[4];
    const float* b1   = (const float*)d_in[5];
    const float* W2   = (const float*)d_in[6];
    const float* b2   = (const float*)d_in[7];
    const float* W3   = (const float*)d_in[8];
    const float* b3   = (const float*)d_in[9];
    const float* W4   = (const float*)d_in[10];
    const float* b4   = (const float*)d_in[11];
    const float* Wfc  = (const float*)d_in[12];
    const float* bfc  = (const float*)d_in[13];
    float* out = (float*)d_out;

    const int N = in_sizes[0] / 64;
    const int E = in_sizes[1] / 2;
    const int G = out_size;
    const int* srcp = ei;
    const int* dstp = ei + E;
    const int NB = (N + BKT_SZ - 1) >> BKT_LG;   // 98 for N=100k

    // workspace layout (float-sized slots)
    float* wsf = (float*)d_ws;
    const size_t Npad = ((size_t)N + 1023) / 1024 * 1024;
    const size_t Epad = ((size_t)E + 1023) / 1024 * 1024;
    float*    dinv   = wsf;                            // Npad
    int*      rowptr = (int*)(wsf + Npad);             // Npad + 1024
    int*      col    = (int*)(wsf + 2 * Npad + 1024);  // Epad
    unsigned* binned = (unsigned*)((float*)col + Epad);// Epad
    int*      bcnt   = (int*)((float*)binned + Epad);  // 256
    int*      base   = bcnt + 256;                     // 256
    int*      bfill  = base + 256;                     // 256
    float*    psum   = (float*)(bfill + 256);          // 256
    int*      pcnt   = (int*)(psum + 256);             // 256
    float*    T1     = psum + 1024;                    // Npad*64
    float*    T2     = T1 + Npad * 64;                 // Npad*64
    float*    H1     = T2 + Npad * 64;                 // Npad*128

    const int gN   = (N + 255) / 256;
    const int gN16 = (N * 16 + 255) / 256;
    const int nbin = (E + BIN_CHUNK - 1) / BIN_CHUNK;

    hipMemsetAsync(bcnt, 0, 256 * sizeof(int), stream);
    hipMemsetAsync(psum, 0, 512 * sizeof(float), stream);

    // ---- CSR build (by dst, col = src) + dinv
    bhist_kernel<<<256, 256, 0, stream>>>(dstp, bcnt, E, NB);
    bscan_kernel<<<1, 128, 0, stream>>>(bcnt, base, bfill, NB, E);
    bin_kernel<<<nbin, 256, 0, stream>>>(srcp, dstp, bfill, binned, E, NB);
    group_kernel<<<NB, 256, 0, stream>>>(binned, base, rowptr, col, dinv, N, E);

    // ---- layer 1: aggregate X (dim 64) first, then GEMM 64->128 + bias + relu
    scale_kernel<<<gN16, 256, 0, stream>>>(x, dinv, T1, N);
    gather_kernel<16, false><<<(N + 15) / 16, 256, 0, stream>>>(T1, rowptr, col, dinv, nullptr, T2, N);
    gemm_kernel<64, 128, 4, 0><<<(N + 31) / 32, 256, 0, stream>>>(T2, W1, b1, nullptr, H1, N);

    // ---- layer 2: GEMM 128->64 (scale by dinv), gather(bias+relu)
    gemm_kernel<128, 64, 2, 1><<<(N + 31) / 32, 256, 0, stream>>>(H1, W2, nullptr, dinv, T1, N);
    gather_kernel<16, true><<<(N + 15) / 16, 256, 0, stream>>>(T1, rowptr, col, dinv, b2, T2, N);

    // ---- layer 3: GEMM 64->64
    gemm_kernel<64, 64, 4, 1><<<(N + 63) / 64, 256, 0, stream>>>(T2, W3, nullptr, dinv, T1, N);
    gather_kernel<16, true><<<(N + 15) / 16, 256, 0, stream>>>(T1, rowptr, col, dinv, b3, T2, N);

    // ---- layer 4: GEMM 64->32
    gemm_kernel<64, 32, 4, 1><<<(N + 127) / 128, 256, 0, stream>>>(T2, W4, nullptr, dinv, T1, N);
    gather_kernel<8, true><<<(N + 31) / 32, 256, 0, stream>>>(T1, rowptr, col, dinv, b4, T2, N);

    // ---- pool + fc
    pool_kernel<<<gN, 256, 0, stream>>>(T2, Wfc, batch, psum, pcnt, N);
    final_kernel<<<1, 256, 0, stream>>>(psum, pcnt, bfc, out, G);
}